// Round 1
// baseline (254.024 us; speedup 1.0000x reference)
//
#include <hip/hip_runtime.h>
#include <math.h>

#define BLOCK 256
#define XW 13
#define PW 30

// Per-patient derivative. X[13] states, P[30] params (column order per reference).
__device__ __forceinline__ void dxdt(const float* X, const float* P,
                                     float ai, float cho, float lq, float lf,
                                     float* dx)
{
    const float BW = P[0],  KMAX = P[1],  B   = P[2],  D   = P[3],  KMIN = P[4];
    const float KABS = P[5], F   = P[6],  KP1 = P[7],  KP2 = P[8],  KP3  = P[9];
    const float FSNC = P[10], KE1 = P[11], KE2 = P[12], K1 = P[13], K2   = P[14];
    const float VM0 = P[15], VMX = P[16], KM0 = P[17], M1 = P[18], M2   = P[19];
    const float M4  = P[20], KA1 = P[21], KA2 = P[22], VI = P[23], P2U  = P[24];
    const float IB  = P[25], KI  = P[26], M30 = P[27], KD = P[28], KSC  = P[29];

    const float f_insulin = ai * 6000.0f / BW;
    const float qsto = X[0] + X[1];
    const float Dbar = lq + lf;

    dx[0] = -KMAX * X[0] + cho * 1000.0f;

    const float inv_dbar = 1.0f / (Dbar + 1e-7f);
    const float aa = 2.5f / (1.0f - B) * inv_dbar;
    const float cc = 2.5f / D * inv_dbar;
    const float kgut_true = KMIN + (KMAX - KMIN) * 0.5f *
        (tanhf(aa * (qsto - B * Dbar)) - tanhf(cc * (qsto - D * Dbar)) + 2.0f);
    const float kgut = (Dbar > 0.0f) ? kgut_true : KMAX;

    dx[1] = KMAX * X[0] - X[1] * kgut;
    dx[2] = kgut * X[1] - KABS * X[2];

    const float Rat  = F * KABS * X[2] / BW;
    const float EGPt = KP1 - KP2 * X[3] - KP3 * X[8];
    const float Et   = (X[3] > KE2) ? KE1 * (X[3] - KE2) : 0.0f;
    const float d3 = fmaxf(EGPt, 0.0f) + Rat - FSNC - Et - K1 * X[3] + K2 * X[4];
    dx[3] = (X[3] >= 0.0f) ? d3 : 0.0f;

    const float Vmt  = VM0 + VMX * X[6];
    const float Uidt = Vmt * X[4] / (KM0 + X[4]);
    const float d4 = -Uidt + K1 * X[3] - K2 * X[4];
    dx[4] = (X[4] >= 0.0f) ? d4 : 0.0f;

    const float d5 = -(M2 + M4) * X[5] + M1 * X[9] + KA1 * X[10] + KA2 * X[11];
    const float It = X[5] / VI;
    dx[5] = (X[5] >= 0.0f) ? d5 : 0.0f;

    dx[6] = -P2U * X[6] + P2U * (It - IB);
    dx[7] = -KI * (X[7] - It);
    dx[8] = -KI * (X[8] - X[7]);

    const float d9 = -(M1 + M30) * X[9] + M2 * X[5];
    dx[9] = (X[9] >= 0.0f) ? d9 : 0.0f;

    const float d10 = f_insulin - (KA1 + KD) * X[10];
    dx[10] = (X[10] >= 0.0f) ? d10 : 0.0f;

    const float d11 = KD * X[10] - KA2 * X[11];
    dx[11] = (X[11] >= 0.0f) ? d11 : 0.0f;

    const float d12 = -KSC * X[12] + KSC * X[3];
    dx[12] = (X[12] >= 0.0f) ? d12 : 0.0f;
}

__global__ __launch_bounds__(BLOCK) void t1d_kernel(
    const float* __restrict__ x,
    const float* __restrict__ params,
    const float* __restrict__ action_ins,
    const float* __restrict__ action_CHO,
    const float* __restrict__ last_Qsto,
    const float* __restrict__ last_foodtaken,
    float* __restrict__ out, int n)
{
    // 44 KB LDS: x tile (reused as output staging) + params tile.
    __shared__ float xbuf[BLOCK * XW];   // 3328 f32 = 13312 B
    __shared__ float pbuf[BLOCK * PW];   // 7680 f32 = 30720 B

    const int tid = threadIdx.x;
    const size_t base = (size_t)blockIdx.x * BLOCK;

    if (base + BLOCK <= (size_t)n) {
        // ---- coalesced float4 staging: global -> LDS ----
        // x rows for this block start at base*13 floats; base is a multiple of
        // 256 so base*13*4 bytes is 16B-aligned. Same for params (base*30).
        const float4* xg = (const float4*)(x + base * XW);
        float4*       xl = (float4*)xbuf;
        for (int k = tid; k < BLOCK * XW / 4; k += BLOCK)   // 832 float4
            xl[k] = xg[k];
        const float4* pg = (const float4*)(params + base * PW);
        float4*       pl = (float4*)pbuf;
        for (int k = tid; k < BLOCK * PW / 4; k += BLOCK)   // 1920 float4
            pl[k] = pg[k];

        // per-patient scalars are already perfectly coalesced in global
        const float ai  = action_ins[base + tid];
        const float cho = action_CHO[base + tid];
        const float lq  = last_Qsto[base + tid];
        const float lf  = last_foodtaken[base + tid];

        __syncthreads();

        // ---- per-row LDS reads (stride 13: conflict-free; stride 30: 4-way, cheap) ----
        float X[XW], P[PW], dx[XW];
        #pragma unroll
        for (int j = 0; j < XW; ++j) X[j] = xbuf[tid * XW + j];
        #pragma unroll
        for (int j = 0; j < PW; ++j) P[j] = pbuf[tid * PW + j];

        dxdt(X, P, ai, cho, lq, lf, dx);

        // own-row overwrite of xbuf needs no barrier (no cross-thread access
        // of x rows in the compute phase)
        #pragma unroll
        for (int j = 0; j < XW; ++j) xbuf[tid * XW + j] = dx[j];

        __syncthreads();

        // ---- coalesced float4 store: LDS -> global ----
        float4* og = (float4*)(out + base * XW);
        for (int k = tid; k < BLOCK * XW / 4; k += BLOCK)
            og[k] = xl[k];
    } else {
        // tail block (not hit for N=2^20, kept for generality): scalar path
        const size_t i = base + tid;
        if (i < (size_t)n) {
            float X[XW], P[PW], dx[XW];
            #pragma unroll
            for (int j = 0; j < XW; ++j) X[j] = x[i * XW + j];
            #pragma unroll
            for (int j = 0; j < PW; ++j) P[j] = params[i * PW + j];
            dxdt(X, P, action_ins[i], action_CHO[i], last_Qsto[i],
                 last_foodtaken[i], dx);
            #pragma unroll
            for (int j = 0; j < XW; ++j) out[i * XW + j] = dx[j];
        }
    }
}

extern "C" void kernel_launch(void* const* d_in, const int* in_sizes, int n_in,
                              void* d_out, int out_size, void* d_ws, size_t ws_size,
                              hipStream_t stream) {
    const float* x      = (const float*)d_in[0];
    const float* params = (const float*)d_in[1];
    const float* ai     = (const float*)d_in[2];
    const float* cho    = (const float*)d_in[3];
    const float* lq     = (const float*)d_in[4];
    const float* lf     = (const float*)d_in[5];
    float* out = (float*)d_out;

    const int n = in_sizes[0] / XW;          // number of patients
    const int grid = (n + BLOCK - 1) / BLOCK;
    t1d_kernel<<<grid, BLOCK, 0, stream>>>(x, params, ai, cho, lq, lf, out, n);
}